// Round 2
// baseline (340.559 us; speedup 1.0000x reference)
//
#include <hip/hip_runtime.h>

typedef short bf16x8 __attribute__((ext_vector_type(8)));
typedef float f32x4 __attribute__((ext_vector_type(4)));
typedef unsigned short u16x4 __attribute__((ext_vector_type(4)));

__device__ __forceinline__ unsigned short f2b(float f) {
    unsigned int u = __builtin_bit_cast(unsigned int, f);
    u += 0x7fffu + ((u >> 16) & 1u);   // RNE
    return (unsigned short)(u >> 16);
}
__device__ __forceinline__ float b2f(unsigned short s) {
    unsigned int u = ((unsigned int)s) << 16;
    return __builtin_bit_cast(float, u);
}

// wt[k][i][j] = bf16(w1[j][k][i]);  k<3, i<128, j<64
__global__ void wt_prepass(const float* __restrict__ w1, unsigned short* __restrict__ wt) {
    int t = blockIdx.x * 256 + threadIdx.x;
    if (t >= 24576) return;
    int j = t & 63;
    int i = (t >> 6) & 127;
    int k = t >> 13;
    wt[t] = f2b(w1[(j * 3 + k) * 128 + i]);
}

// xs row index = a*13 + s (pitch 13 -> (row&7) sweeps all 8 swizzle slots)
// xs byte addr = (row<<7) + ((j*2) ^ ((row&7)<<4))
#define TP 74   // t4s pitch in u16

__global__ __launch_bounds__(256, 3) void fused_main(
        const float* __restrict__ x, const float* __restrict__ w0,
        const unsigned short* __restrict__ wt, float* __restrict__ y) {
    __shared__ __align__(16) char smem[28 * 13 * 64 * 2];        // 46592 B: xs, later t4s
    __shared__ __align__(16) unsigned short raws[224 * 12];      // 5376 B raw chunk
    __shared__ float w0s[256];
    unsigned short* t4s = (unsigned short*)smem;

    const int tid  = threadIdx.x;
    const int lane = tid & 63;
    const int w    = tid >> 6;
    // XCD-chunked swizzle: 4096 blocks, 8 XCDs -> bc-siblings share an XCD
    const int bid  = ((int)blockIdx.x & 7) * 512 + ((int)blockIdx.x >> 3);
    const int b    = bid >> 2;
    const int bc   = bid & 3;
    const int c0   = 7 * bc;
    const int rl   = lane & 15;
    const int jb0  = (lane >> 4) << 3;

    w0s[tid] = w0[tid];

    // window float4 columns per bc
    int q0, q1, q2;
    if      (bc == 0) { q0 = 0; q1 = 1; q2 = 6; }
    else if (bc == 1) { q0 = 1; q1 = 2; q2 = 3; }
    else if (bc == 2) { q0 = 3; q1 = 4; q2 = 5; }
    else              { q0 = 4; q1 = 5; q2 = 6; }

    // slot -> raw column index (-1 => zero)
    int off[12];
#pragma unroll
    for (int s = 0; s < 12; ++s) {
        if      (bc == 0) off[s] = (s < 2) ? 10 + s : ((s < 4) ? -1 : s - 4);
        else if (bc == 1) off[s] = (s < 10) ? s + 1 : -1;
        else if (bc == 2) off[s] = (s < 10) ? s : -1;
        else              off[s] = (s < 9) ? s + 3 : -1;
    }

    const int a_t   = tid % 28;          // for transpose phase (tid<224)
    const int jq_t  = tid / 28;
    const int rowb  = a_t * 13;

    // ---- staged transpose of x window into xs, 8 chunks of 224 rows ----
    const size_t xb = (size_t)b * (1792 * 28);
    for (int c = 0; c < 8; ++c) {
        for (int f = tid; f < 672; f += 256) {
            int rowl = f / 3;
            int q3   = f - rowl * 3;
            int q    = (q3 == 0) ? q0 : ((q3 == 1) ? q1 : q2);
            const float4 v = *reinterpret_cast<const float4*>(
                x + xb + (size_t)(c * 224 + rowl) * 28 + q * 4);
            u16x4 hv;
            hv.x = f2b(v.x); hv.y = f2b(v.y); hv.z = f2b(v.z); hv.w = f2b(v.w);
            *reinterpret_cast<u16x4*>(raws + rowl * 12 + q3 * 4) = hv;
        }
        __syncthreads();
        if (tid < 224) {
            const int j2 = (c * 8 + jq_t) * 2;
#pragma unroll
            for (int s = 0; s < 12; ++s) {
                unsigned short v = (off[s] >= 0) ? raws[tid * 12 + off[s]] : (unsigned short)0;
                int row  = rowb + s;
                int byte = (row << 7) + (j2 ^ ((row & 7) << 4));
                *(unsigned short*)(smem + byte) = v;
            }
        }
        __syncthreads();
    }

    // ---- K-loop: per wave 14 m-tiles x 2 n-tiles, 6 K-steps of 32 ----
    const int cl = rl & 7;
    const int rh = rl >> 3;
    int rowoff[3];
#pragma unroll
    for (int k = 0; k < 3; ++k) {
        int sIdx = (bc == 0) ? ((cl == 0) ? k : (cl + k + 2)) : (cl + k);
        rowoff[k] = rh * 13 + sIdx;
    }

    f32x4 acc[14][2];
#pragma unroll
    for (int mt = 0; mt < 14; ++mt) {
        acc[mt][0] = f32x4{0.f, 0.f, 0.f, 0.f};
        acc[mt][1] = f32x4{0.f, 0.f, 0.f, 0.f};
    }

#pragma unroll
    for (int s = 0; s < 6; ++s) {
        const int k  = s >> 1;
        const int jb = ((s & 1) << 5) + jb0;
        const int jx = jb << 1;
        bf16x8 b0 = *reinterpret_cast<const bf16x8*>(wt + (k << 13) + (((w << 5) + rl) << 6) + jb);
        bf16x8 b1 = *reinterpret_cast<const bf16x8*>(wt + (k << 13) + (((w << 5) + 16 + rl) << 6) + jb);
#pragma unroll
        for (int mt = 0; mt < 14; ++mt) {
            int row  = 26 * mt + rowoff[k];
            int byte = (row << 7) + (jx ^ ((row & 7) << 4));
            bf16x8 af = *reinterpret_cast<const bf16x8*>(smem + byte);
            acc[mt][0] = __builtin_amdgcn_mfma_f32_16x16x32_bf16(af, b0, acc[mt][0], 0, 0, 0);
            acc[mt][1] = __builtin_amdgcn_mfma_f32_16x16x32_bf16(af, b1, acc[mt][1], 0, 0, 0);
        }
    }
    __syncthreads();

    // ---- epilogue: two i-halves through swizzled t4s ----
#pragma unroll
    for (int h = 0; h < 2; ++h) {
        if ((w >> 1) == h) {
            int icbase = ((w & 1) << 5) + rl;
            int rq = (lane >> 4) << 2;
#pragma unroll
            for (int mt = 0; mt < 14; ++mt) {
#pragma unroll
                for (int p = 0; p < 2; ++p) {
                    int ic = icbase + (p << 4);
#pragma unroll
                    for (int q = 0; q < 4; ++q) {
                        int r    = (mt << 4) + rq + q;
                        int byte = r * (TP * 2) + ((ic * 2) ^ (((r >> 5) & 7) << 4));
                        *(unsigned short*)((char*)t4s + byte) = f2b(acc[mt][p][q]);
                    }
                }
            }
        }
        __syncthreads();
        for (int f = tid; f < 64 * 49; f += 256) {
            int lq    = f % 7;
            int t1    = f / 7;
            int m_loc = t1 % 7;
            int iloc  = t1 / 7;
            int i = (h << 6) + iloc;
            float w00 = w0s[2 * i], w01 = w0s[2 * i + 1];
            int m = c0 + m_loc;
            float ov[4];
#pragma unroll
            for (int u = 0; u < 4; ++u) {
                int l  = (lq << 2) + u;
                int ap = (l == 0) ? 27 : (l - 1);
                int r1 = (ap << 3) + m_loc + 1;       // c = m
                int r2 = (ap << 3) + m_loc;           // c = m-1 (mod 28 via block wrap)
                int by1 = r1 * (TP * 2) + ((iloc * 2) ^ (((r1 >> 5) & 7) << 4));
                int by2 = r2 * (TP * 2) + ((iloc * 2) ^ (((r2 >> 5) & 7) << 4));
                float v1 = b2f(*(unsigned short*)((char*)t4s + by1));
                float v2 = b2f(*(unsigned short*)((char*)t4s + by2));
                ov[u] = w00 * v1 + w01 * v2;
            }
            float4 o; o.x = ov[0]; o.y = ov[1]; o.z = ov[2]; o.w = ov[3];
            *reinterpret_cast<float4*>(y + ((((size_t)b * 128 + i) * 28 + m) * 28) + (lq << 2)) = o;
        }
        __syncthreads();
    }
}

extern "C" void kernel_launch(void* const* d_in, const int* in_sizes, int n_in,
                              void* d_out, int out_size, void* d_ws, size_t ws_size,
                              hipStream_t stream) {
    const float* x  = (const float*)d_in[0];
    const float* w0 = (const float*)d_in[1];
    const float* w1 = (const float*)d_in[2];
    unsigned short* wt = (unsigned short*)d_ws;   // 24576 u16 = 48 KiB
    float* y = (float*)d_out;

    hipLaunchKernelGGL(wt_prepass, dim3(96), dim3(256), 0, stream, w1, wt);
    hipLaunchKernelGGL(fused_main, dim3(4096), dim3(256), 0, stream, x, w0, wt, y);
}

// Round 3
// 314.544 us; speedup vs baseline: 1.0827x; 1.0827x over previous
//
#include <hip/hip_runtime.h>

typedef short bf16x8 __attribute__((ext_vector_type(8)));
typedef float f32x4 __attribute__((ext_vector_type(4)));
typedef unsigned short u16x4 __attribute__((ext_vector_type(4)));

__device__ __forceinline__ unsigned short f2b(float f) {
    unsigned int u = __builtin_bit_cast(unsigned int, f);
    u += 0x7fffu + ((u >> 16) & 1u);   // RNE
    return (unsigned short)(u >> 16);
}
__device__ __forceinline__ float b2f(unsigned short s) {
    unsigned int u = ((unsigned int)s) << 16;
    return __builtin_bit_cast(float, u);
}

// ---- wt[k][i][j] = bf16(w1[j][k][i]);  k<3, i<128, j<64 ----
__global__ void wt_prepass(const float* __restrict__ w1, unsigned short* __restrict__ wt) {
    int t = blockIdx.x * 256 + threadIdx.x;
    if (t >= 24576) return;
    int j = t & 63;
    int i = (t >> 6) & 127;
    int k = t >> 13;
    wt[t] = f2b(w1[(j * 3 + k) * 128 + i]);
}

// ---- xt[b][a][np][j] = bf16(x[b][j*28+a][np-1]); np==0 and np==29 are zero rows ----
// block = (b, jh): jh selects j-half [32jh, 32jh+32)
__global__ __launch_bounds__(256, 3) void xt_prepass(const float* __restrict__ x,
                                                     unsigned short* __restrict__ xt) {
    __shared__ unsigned short lds[896 * 29];   // [r = jl*28+a][n], pitch 29
    const int tid = threadIdx.x;
    const int b   = blockIdx.x >> 1;
    const int jh  = blockIdx.x & 1;
    const float* xb = x + (size_t)b * (1792 * 28) + (size_t)jh * (896 * 28);

    // phase A: coalesced float4 reads of 896 x-rows -> bf16 LDS
    for (int f = tid; f < 6272; f += 256) {
        int r = f / 7, q = f - r * 7;
        float4 v = *reinterpret_cast<const float4*>(xb + r * 28 + q * 4);
        int base = r * 29 + q * 4;
        lds[base + 0] = f2b(v.x);
        lds[base + 1] = f2b(v.y);
        lds[base + 2] = f2b(v.z);
        lds[base + 3] = f2b(v.w);
    }
    __syncthreads();

    // phase B: write xt rows (a, np), 32 j per block-half, 4 j per thread-chunk
    unsigned short* xtb = xt + (size_t)b * (28 * 30 * 64) + jh * 32;
    for (int g = tid; g < 6720; g += 256) {
        int t  = g & 7;                 // j-quad within half
        int np = (g >> 3) % 30;
        int a  = g / 240;
        u16x4 o;
        if (np == 0 || np == 29) {
            o.x = 0; o.y = 0; o.z = 0; o.w = 0;
        } else {
            int n  = np - 1;
            int jl = t * 4;
            o.x = lds[(jl + 0) * 812 + a * 29 + n];
            o.y = lds[(jl + 1) * 812 + a * 29 + n];
            o.z = lds[(jl + 2) * 812 + a * 29 + n];
            o.w = lds[(jl + 3) * 812 + a * 29 + n];
        }
        *reinterpret_cast<u16x4*>(xtb + ((size_t)(a * 30 + np) << 6) + t * 4) = o;
    }
}

// xs row = a*13 + s (pitch 13 sweeps all 8 swizzle phases); byte = (row<<7) + (j2 ^ ((row&7)<<4))
#define TP 74   // t4s pitch in u16

__global__ __launch_bounds__(256, 3) void fused_main(
        const unsigned short* __restrict__ xt, const float* __restrict__ w0,
        const unsigned short* __restrict__ wt, float* __restrict__ y) {
    __shared__ __align__(16) char smem[364 * 128];   // 46592 B: xs, later t4s
    __shared__ float w0s[256];
    unsigned short* t4s = (unsigned short*)smem;

    const int tid  = threadIdx.x;
    const int lane = tid & 63;
    const int w    = tid >> 6;
    const int b    = blockIdx.x >> 2;    // identity mapping (swizzle reverted)
    const int bc   = blockIdx.x & 3;
    const int c0   = 7 * bc;
    const int rl   = lane & 15;
    const int jb0  = (lane >> 4) << 3;

    w0s[tid] = w0[tid];

    // ---- stage xt slab -> xs (coalesced 16B chunks, XOR-swizzled dest) ----
    const unsigned short* xtb = xt + (size_t)b * (28 * 30 * 64);
    for (int f = tid; f < 2688; f += 256) {
        int jc = f & 7;
        int s  = (f >> 3) % 12;
        int a  = f / 96;
        int np;
        if (bc == 0) np = (s < 9) ? s : (s + 18);          // 9,10,11 -> 27,28,29
        else { np = c0 - 1 + s; if (np > c0 + 8) np = c0 + 8; }   // s>=10 unused
        bf16x8 v = *reinterpret_cast<const bf16x8*>(xtb + ((size_t)(a * 30 + np) << 6) + (jc << 3));
        int row  = a * 13 + s;
        int byte = (row << 7) + ((jc << 4) ^ ((row & 7) << 4));
        *reinterpret_cast<bf16x8*>(smem + byte) = v;
    }
    __syncthreads();

    // ---- K-loop: per wave 14 m-tiles x 2 n-tiles, 6 K-steps of 32 ----
    const int cl = rl & 7;
    const int rh = rl >> 3;
    int rowoff[3];
#pragma unroll
    for (int k = 0; k < 3; ++k) {
        int sIdx = (bc == 0) ? ((cl == 0) ? (9 + k) : (cl - 1 + k)) : (cl + k);
        rowoff[k] = rh * 13 + sIdx;
    }

    f32x4 acc[14][2];
#pragma unroll
    for (int mt = 0; mt < 14; ++mt) {
        acc[mt][0] = f32x4{0.f, 0.f, 0.f, 0.f};
        acc[mt][1] = f32x4{0.f, 0.f, 0.f, 0.f};
    }

#pragma unroll
    for (int s = 0; s < 6; ++s) {
        const int k  = s >> 1;
        const int jb = ((s & 1) << 5) + jb0;
        const int jx = jb << 1;
        bf16x8 b0 = *reinterpret_cast<const bf16x8*>(wt + (k << 13) + (((w << 5) + rl) << 6) + jb);
        bf16x8 b1 = *reinterpret_cast<const bf16x8*>(wt + (k << 13) + (((w << 5) + 16 + rl) << 6) + jb);
#pragma unroll
        for (int mt = 0; mt < 14; ++mt) {
            int row  = 26 * mt + rowoff[k];
            int byte = (row << 7) + (jx ^ ((row & 7) << 4));
            bf16x8 af = *reinterpret_cast<const bf16x8*>(smem + byte);
            acc[mt][0] = __builtin_amdgcn_mfma_f32_16x16x32_bf16(af, b0, acc[mt][0], 0, 0, 0);
            acc[mt][1] = __builtin_amdgcn_mfma_f32_16x16x32_bf16(af, b1, acc[mt][1], 0, 0, 0);
        }
    }
    __syncthreads();

    // ---- epilogue: two i-halves through swizzled t4s ----
#pragma unroll
    for (int h = 0; h < 2; ++h) {
        if ((w >> 1) == h) {
            int icbase = ((w & 1) << 5) + rl;
            int rq = (lane >> 4) << 2;
#pragma unroll
            for (int mt = 0; mt < 14; ++mt) {
#pragma unroll
                for (int p = 0; p < 2; ++p) {
                    int ic = icbase + (p << 4);
#pragma unroll
                    for (int q = 0; q < 4; ++q) {
                        int r    = (mt << 4) + rq + q;
                        int byte = r * (TP * 2) + ((ic * 2) ^ (((r >> 5) & 7) << 4));
                        *(unsigned short*)((char*)t4s + byte) = f2b(acc[mt][p][q]);
                    }
                }
            }
        }
        __syncthreads();
        for (int f = tid; f < 64 * 49; f += 256) {
            int lq    = f % 7;
            int t1    = f / 7;
            int m_loc = t1 % 7;
            int iloc  = t1 / 7;
            int i = (h << 6) + iloc;
            float w00 = w0s[2 * i], w01 = w0s[2 * i + 1];
            int m = c0 + m_loc;
            float ov[4];
#pragma unroll
            for (int u = 0; u < 4; ++u) {
                int l  = (lq << 2) + u;
                int ap = (l == 0) ? 27 : (l - 1);
                int r1 = (ap << 3) + m_loc + 1;       // c = m
                int r2 = (ap << 3) + m_loc;           // c = m-1 (mod 28 via block map)
                int by1 = r1 * (TP * 2) + ((iloc * 2) ^ (((r1 >> 5) & 7) << 4));
                int by2 = r2 * (TP * 2) + ((iloc * 2) ^ (((r2 >> 5) & 7) << 4));
                float v1 = b2f(*(unsigned short*)((char*)t4s + by1));
                float v2 = b2f(*(unsigned short*)((char*)t4s + by2));
                ov[u] = w00 * v1 + w01 * v2;
            }
            float4 o; o.x = ov[0]; o.y = ov[1]; o.z = ov[2]; o.w = ov[3];
            *reinterpret_cast<float4*>(y + ((((size_t)b * 128 + i) * 28 + m) * 28) + (lq << 2)) = o;
        }
        __syncthreads();
    }
}

extern "C" void kernel_launch(void* const* d_in, const int* in_sizes, int n_in,
                              void* d_out, int out_size, void* d_ws, size_t ws_size,
                              hipStream_t stream) {
    const float* x  = (const float*)d_in[0];
    const float* w0 = (const float*)d_in[1];
    const float* w1 = (const float*)d_in[2];
    float* y = (float*)d_out;

    // workspace layout: xt (1024*28*30*64 u16 = 110,100,480 B) then wt (49,152 B)
    unsigned short* xt = (unsigned short*)d_ws;
    unsigned short* wt = (unsigned short*)((char*)d_ws + (size_t)1024 * 28 * 30 * 64 * 2);

    hipLaunchKernelGGL(wt_prepass, dim3(96), dim3(256), 0, stream, w1, wt);
    hipLaunchKernelGGL(xt_prepass, dim3(2048), dim3(256), 0, stream, x, xt);
    hipLaunchKernelGGL(fused_main, dim3(4096), dim3(256), 0, stream, xt, w0, wt, y);
}